// Round 13
// baseline (244.545 us; speedup 1.0000x reference)
//
#include <hip/hip_runtime.h>
#include <hip/hip_bf16.h>

#define NRELS 8
#define NB 8
#define PBLK 256          // partition blocks
#define BSH 9             // dsts per bucket = 512
#define BCAP 3584         // max edges per bucket staged in LDS

typedef __attribute__((ext_vector_type(8))) short short8v;
typedef __attribute__((ext_vector_type(4))) float f32x4;

__device__ __forceinline__ short bfc(float f) {
    __hip_bfloat16 h = __float2bfloat16(f);
    return *reinterpret_cast<short*>(&h);
}
__device__ __forceinline__ float bf2f(ushort u) {
    return __uint_as_float((unsigned)u << 16);
}
__device__ __forceinline__ short8v cvt8(float4 a, float4 b) {
    short8v r;
    r[0] = bfc(a.x); r[1] = bfc(a.y); r[2] = bfc(a.z); r[3] = bfc(a.w);
    r[4] = bfc(b.x); r[5] = bfc(b.y); r[6] = bfc(b.z); r[7] = bfc(b.w);
    return r;
}

// ---- W in MFMA B-frag order, 8-consecutive-col-per-lane packing (verified R8).
__global__ void wprep_kernel(const float* __restrict__ basis1, const float* __restrict__ comp1,
                             const float* __restrict__ basis2, const float* __restrict__ comp2,
                             short* __restrict__ Wf1, short* __restrict__ Wf2) {
    int idx = blockIdx.x * blockDim.x + threadIdx.x;
    const int n1 = 64 * 512;
    const int n2 = 32 * 512;
    if (idx < n1) {
        int f = idx >> 9, lane = (idx >> 3) & 63, j = idx & 7;
        int ks = f & 1, q = (f >> 1) & 7, gg = f >> 4;
        int c = gg * 128 + 8 * (lane & 15) + q;
        int k = ks * 32 + (lane >> 4) * 8 + j;
        int r = c >> 6, crel = c & 63;
        float s = 0.f;
#pragma unroll
        for (int b = 0; b < NB; ++b)
            s = fmaf(comp1[r * NB + b], basis1[b * 4096 + k * 64 + crel], s);
        Wf1[idx] = bfc(s);
    } else if (idx < n1 + n2) {
        int i2 = idx - n1;
        int f = i2 >> 9, lane = (i2 >> 3) & 63, j = i2 & 7;
        int ks = f & 1, q = (f >> 1) & 7, gg = f >> 4;
        int c = gg * 128 + 8 * (lane & 15) + q;
        int k = ks * 32 + (lane >> 4) * 8 + j;
        int r = c >> 5, crel = c & 31;
        float s = 0.f;
#pragma unroll
        for (int b = 0; b < NB; ++b)
            s = fmaf(comp2[r * NB + b], basis2[b * 2048 + k * 32 + crel], s);
        Wf2[i2] = bfc(s);
    }
}

// =================== sort bodies (device functions) ===================
__device__ __forceinline__ void histA_body(const int* __restrict__ dst, int* __restrict__ histM,
                                           int nEdges, int nBuck, int chunk, int bid) {
    __shared__ int h[512];
    for (int t = threadIdx.x; t < nBuck; t += 256) h[t] = 0;
    __syncthreads();
    int start = bid * chunk;
    int end = min(nEdges, start + chunk);
    for (int i = start + threadIdx.x; i < end; i += 256)
        atomicAdd(&h[dst[i] >> BSH], 1);
    __syncthreads();
    for (int t = threadIdx.x; t < nBuck; t += 256)
        histM[t * PBLK + bid] = h[t];
}

// 256-thread scan over up to 512 buckets (2 elems/thread Hillis-Steele)
__device__ __forceinline__ void scanA_body(const int* __restrict__ histM, int* __restrict__ offs,
                                           int* __restrict__ bucketBase, int nBuck, int nBlk,
                                           int nEdges) {
    __shared__ int tot[512];
    const int tid = threadIdx.x;
    int sums[2] = {0, 0};
#pragma unroll
    for (int half = 0; half < 2; ++half) {
        int b = tid + half * 256;
        if (b < nBuck) {
            const int4* hp = (const int4*)(histM + b * nBlk);
            int s = 0;
            for (int k = 0; k < nBlk / 4; ++k) {
                int4 v = hp[k];
                s += v.x + v.y + v.z + v.w;
            }
            sums[half] = s;
        }
        tot[b] = sums[half];
    }
    __syncthreads();
    for (int st = 1; st < 512; st <<= 1) {
        int t0 = (tid >= st) ? tot[tid - st] : 0;
        int t1 = tot[tid + 256 - st];
        __syncthreads();
        tot[tid] += t0;
        tot[tid + 256] += t1;
        __syncthreads();
    }
#pragma unroll
    for (int half = 0; half < 2; ++half) {
        int b = tid + half * 256;
        if (b < nBuck) {
            int base = tot[b] - sums[half];   // exclusive
            bucketBase[b] = base;
            int run = base;
            const int4* hp = (const int4*)(histM + b * nBlk);
            int4* op = (int4*)(offs + b * nBlk);
            for (int k = 0; k < nBlk / 4; ++k) {
                int4 h4 = hp[k];
                int4 o4;
                o4.x = run; run += h4.x;
                o4.y = run; run += h4.y;
                o4.z = run; run += h4.z;
                o4.w = run; run += h4.w;
                op[k] = o4;
            }
        }
    }
    if (tid == 0) bucketBase[nBuck] = nEdges;
}

__device__ __forceinline__ void part_body(const int* __restrict__ src, const int* __restrict__ dst,
                                          const int* __restrict__ et, const float* __restrict__ norm,
                                          const int* __restrict__ offs, uint2* __restrict__ staged,
                                          int nEdges, int nBuck, int chunk, int bid) {
    __shared__ int cur[512];
    for (int t = threadIdx.x; t < nBuck; t += 256)
        cur[t] = offs[t * PBLK + bid];
    __syncthreads();
    int start = bid * chunk;
    int end = min(nEdges, start + chunk);
    for (int i = start + threadIdx.x; i < end; i += 256) {
        int d = dst[i];
        int b = d >> BSH;
        int p = atomicAdd(&cur[b], 1);
        staged[p] = make_uint2(((unsigned)(d & 511) << 21) |
                               ((unsigned)src[i] << 3) | (unsigned)et[i],
                               __float_as_uint(norm[i]));
    }
}

__device__ __forceinline__ void sortB_body(uint2* __restrict__ meta,
                                           const int* __restrict__ bucketBase,
                                           int* __restrict__ endOff, int nNodes, int bid) {
    const int tid = threadIdx.x;
    const int e0 = bucketBase[bid];
    const int n = min(bucketBase[bid + 1] - e0, BCAP);
    __shared__ uint2 st[BCAP];
    __shared__ int h[512];
    __shared__ int pb[256];
    h[2 * tid] = 0; h[2 * tid + 1] = 0;
    __syncthreads();
    for (int j = tid; j < n; j += 256) {
        uint2 v = meta[e0 + j];
        st[j] = v;
        atomicAdd(&h[v.x >> 21], 1);
    }
    __syncthreads();
    int h0 = h[2 * tid], h1v = h[2 * tid + 1];
    int ps = h0 + h1v;
    pb[tid] = ps;
    __syncthreads();
    for (int s = 1; s < 256; s <<= 1) {
        int t = (tid >= s) ? pb[tid - s] : 0;
        __syncthreads();
        pb[tid] += t;
        __syncthreads();
    }
    int ex = pb[tid] - ps;     // exclusive pair base
    int d0 = bid << BSH;
    int dA = d0 + 2 * tid, dB = dA + 1;
    if (dA < nNodes) endOff[dA] = e0 + ex + h0;
    if (dB < nNodes) endOff[dB] = e0 + ex + ps;
    h[2 * tid] = ex;
    h[2 * tid + 1] = ex + h0;
    __syncthreads();
    for (int j = tid; j < n; j += 256) {
        uint2 v = st[j];
        int r = atomicAdd(&h[v.x >> 21], 1);
        meta[e0 + r] = make_uint2(v.x & 0x1FFFFFu, v.y);
    }
}

// =================== transform body (32 nodes/wave, R12-verified) ===================
template <int G128, bool BF16IN>
__device__ __forceinline__ void transform_body(const void* __restrict__ xin,
                                               const short* __restrict__ Wf,
                                               ushort* __restrict__ yb, int nNodes, int wid) {
    constexpr int TOUT = G128 * 128;
    const int lane = threadIdx.x & 63;
    const int base = wid * 32;
    if (base >= nNodes) return;
    const int ml = lane & 15, kg = lane >> 4;

    short8v A[2][2];
#pragma unroll
    for (int s = 0; s < 2; ++s) {
        int row = min(base + s * 16 + ml, nNodes - 1);
        if (BF16IN) {
            const ushort* xp = (const ushort*)xin + (size_t)row * 64 + kg * 8;
            A[s][0] = *(const short8v*)xp;
            A[s][1] = *(const short8v*)(xp + 32);
        } else {
            const float* xp = (const float*)xin + (size_t)row * 64 + kg * 8;
            float4 f0 = *(const float4*)xp;
            float4 f1 = *(const float4*)(xp + 4);
            float4 f2 = *(const float4*)(xp + 32);
            float4 f3 = *(const float4*)(xp + 36);
            A[s][0] = cvt8(f0, f1);
            A[s][1] = cvt8(f2, f3);
        }
    }
#pragma unroll
    for (int gg = 0; gg < G128; ++gg) {
        const short* wp = Wf + (size_t)gg * 16 * 512 + lane * 8;
        f32x4 acc[2][8];
#pragma unroll
        for (int q = 0; q < 8; ++q) {
            short8v B0 = *(const short8v*)(wp + (q * 2 + 0) * 512);
            short8v B1 = *(const short8v*)(wp + (q * 2 + 1) * 512);
#pragma unroll
            for (int s = 0; s < 2; ++s) {
                acc[s][q] = __builtin_amdgcn_mfma_f32_16x16x32_bf16(A[s][0], B0,
                                                                    (f32x4){0.f, 0.f, 0.f, 0.f}, 0, 0, 0);
                acc[s][q] = __builtin_amdgcn_mfma_f32_16x16x32_bf16(A[s][1], B1, acc[s][q], 0, 0, 0);
            }
        }
#pragma unroll
        for (int s = 0; s < 2; ++s) {
#pragma unroll
            for (int i = 0; i < 4; ++i) {
                int row = base + s * 16 + kg * 4 + i;
                if (row < nNodes) {
                    uint4 pk;
                    pk.x = (unsigned)(ushort)bfc(acc[s][0][i]) | ((unsigned)(ushort)bfc(acc[s][1][i]) << 16);
                    pk.y = (unsigned)(ushort)bfc(acc[s][2][i]) | ((unsigned)(ushort)bfc(acc[s][3][i]) << 16);
                    pk.z = (unsigned)(ushort)bfc(acc[s][4][i]) | ((unsigned)(ushort)bfc(acc[s][5][i]) << 16);
                    pk.w = (unsigned)(ushort)bfc(acc[s][6][i]) | ((unsigned)(ushort)bfc(acc[s][7][i]) << 16);
                    *reinterpret_cast<uint4*>(yb + (size_t)row * TOUT + gg * 128 + ml * 8) = pk;
                }
            }
        }
    }
}

template <int G128, bool BF16IN>
__global__ __launch_bounds__(256) void transform_kernel(
    const void* __restrict__ xin, const short* __restrict__ Wf,
    ushort* __restrict__ yb, int nNodes, int waveOff) {
    int wid = waveOff + blockIdx.x * 4 + (threadIdx.x >> 6);
    transform_body<G128, BF16IN>(xin, Wf, yb, nNodes, wid);
}

// =================== edge body (scalarized spine, R12-verified) ===================
template <int OUT, typename OutT, bool ACCUM, int SHIFT>
__device__ __forceinline__ void edge_body(const ushort* __restrict__ yb,
                                          const uint2* __restrict__ meta,
                                          const int* __restrict__ endOff,
                                          const float* __restrict__ bias,
                                          OutT* __restrict__ out, int nNodes, int D,
                                          int wid, int dLo, int dHi) {
    const int lane = threadIdx.x & 63;
    const int o = lane & (OUT - 1);
    const int d0 = dLo + wid * D;
    if (d0 >= dHi) return;
    const int d1 = min(d0 + D, dHi);
    const float bv = bias[o];

    int bndv = 0x7fffffff;
    if (lane < D) bndv = endOff[min(d0 + lane, nNodes - 1)];
    const int eEnd = __builtin_amdgcn_readlane(bndv, d1 - 1 - d0);
    int e = __builtin_amdgcn_readfirstlane((d0 == 0) ? 0 : endOff[d0 - 1]);
    int dcur = d0;
    int bnd = __builtin_amdgcn_readlane(bndv, 0);
    float acc = 0.f;

    auto gv = [&](unsigned key) -> float {
        const ushort* rowp = (const ushort*)((const char*)yb + ((size_t)key << SHIFT));
        return bf2f(rowp[o]);
    };
    auto flushd = [&]() {
        size_t idx = (size_t)dcur * OUT + o;
        if (OUT == 64 || lane < OUT) {
            if constexpr (ACCUM)
                out[idx] = (OutT)(ushort)bfc(bf2f((ushort)out[idx]) + acc);
            else if constexpr (sizeof(OutT) == 2)
                out[idx] = (OutT)(ushort)bfc(bv + acc);
            else
                out[idx] = (OutT)(bv + acc);
        }
        acc = 0.f;
        ++dcur;
        bnd = __builtin_amdgcn_readlane(bndv, dcur - d0);
    };

    if (e < eEnd) {
        const int eL = eEnd - 1;
        uint2 Ma[8], Mb[8];
        float Va[8];
#pragma unroll
        for (int k = 0; k < 8; ++k) Ma[k] = meta[min(e + k, eL)];
#pragma unroll
        for (int k = 0; k < 8; ++k) Mb[k] = meta[min(e + 8 + k, eL)];
#pragma unroll
        for (int k = 0; k < 8; ++k) Va[k] = gv(Ma[k].x);

        const int nFull = (eEnd - e) >> 3;
        for (int blk = 0; blk < nFull; ++blk) {
            float Vb[8];
            uint2 Mc[8];
#pragma unroll
            for (int k = 0; k < 8; ++k) Vb[k] = gv(Mb[k].x);
#pragma unroll
            for (int k = 0; k < 8; ++k) Mc[k] = meta[min(e + 16 + k, eL)];
#pragma unroll
            for (int k = 0; k < 8; ++k) {
                while (e >= bnd) flushd();
                acc = fmaf(__uint_as_float(Ma[k].y), Va[k], acc);
                ++e;
            }
#pragma unroll
            for (int k = 0; k < 8; ++k) { Ma[k] = Mb[k]; Mb[k] = Mc[k]; Va[k] = Vb[k]; }
        }
        const int rem = eEnd - e;
#pragma unroll
        for (int k = 0; k < 8; ++k) {
            if (k < rem) {
                while (e >= bnd) flushd();
                acc = fmaf(__uint_as_float(Ma[k].y), Va[k], acc);
                ++e;
            }
        }
    }
    while (dcur < d1) flushd();
}

template <int OUT, typename OutT, int SHIFT>
__global__ __launch_bounds__(256, 4) void edge_s_kernel(
    const ushort* __restrict__ yb, const uint2* __restrict__ meta,
    const int* __restrict__ endOff, const float* __restrict__ bias,
    OutT* __restrict__ out, int nNodes, int dLo, int dHi) {
    int wid = blockIdx.x * 4 + (threadIdx.x >> 6);
    edge_body<OUT, OutT, false, SHIFT>(yb, meta, endOff, bias, out, nNodes, 8, wid, dLo, dHi);
}

// legacy vector path for the non-fused fallback (rel-windowed Y)
template <int OUT, typename OutT, bool ACCUM>
__global__ __launch_bounds__(256, 4) void edge_f_kernel(
    const ushort* __restrict__ yb, const uint2* __restrict__ meta,
    const int* __restrict__ endOff, const float* __restrict__ bias,
    OutT* __restrict__ out, int nNodes, int D, int rtLo) {
    const int lane = threadIdx.x & 63;
    constexpr int GPW = 64 / OUT;
    const int wid = (blockIdx.x * blockDim.x + threadIdx.x) >> 6;
    const int sub = (GPW == 2) ? (lane >> 5) : 0;
    const int gbase = sub << 5;
    const int gid = wid * GPW + sub;
    const int o = lane & (OUT - 1);
    const int d0 = gid * D;
    if (d0 >= nNodes) return;
    const int d1 = min(d0 + D, nNodes);
    const float bv = bias[o];

    int bndv = 0x7fffffff;
    if (o < D) bndv = endOff[min(d0 + o, nNodes - 1)];
    const int eEnd = __shfl(bndv, gbase + (d1 - 1 - d0));
    int e = (d0 == 0) ? 0 : endOff[d0 - 1];
    int dcur = d0;
    int bnd = __shfl(bndv, gbase);
    float acc = 0.f;

    auto gv = [&](unsigned key) -> float {
        int rr = (int)(key & 7u) - rtLo;
        if ((unsigned)rr >= 4u) return 0.f;
        unsigned off = (((key >> 3) * (unsigned)(4 * OUT)) + (unsigned)rr * OUT +
                        (unsigned)o) << 1;
        return bf2f(*(const ushort*)((const char*)yb + off));
    };
    auto flush = [&](int d, float a) {
        size_t idx = (size_t)d * OUT + o;
        if constexpr (ACCUM) out[idx] = (OutT)(ushort)bfc(bf2f((ushort)out[idx]) + a);
        else if constexpr (sizeof(OutT) == 2) out[idx] = (OutT)(ushort)bfc(bv + a);
        else out[idx] = (OutT)(bv + a);
    };

    for (; e < eEnd; ++e) {
        uint2 M = meta[e];
        while (e >= bnd) {
            flush(dcur, acc); acc = 0.f; ++dcur;
            bnd = __shfl(bndv, gbase + (dcur - d0));
        }
        acc = fmaf(__uint_as_float(M.y), gv(M.x), acc);
    }
    for (; dcur < d1; ++dcur) { flush(dcur, acc); acc = 0.f; }
}

// =================== mega kernels: sort stage || T16 slice ===================
__global__ __launch_bounds__(256) void mk1_kernel(const int* dst, int* histM, int nEdges,
                                                  int nBuck, int chunk, const float* emb,
                                                  const short* Wf1, ushort* yB, int nNodes,
                                                  int waveOff) {
    if ((int)blockIdx.x < PBLK) { histA_body(dst, histM, nEdges, nBuck, chunk, blockIdx.x); return; }
    int wid = waveOff + ((int)blockIdx.x - PBLK) * 4 + ((int)threadIdx.x >> 6);
    transform_body<4, false>(emb, Wf1, yB, nNodes, wid);
}

__global__ __launch_bounds__(256) void mk2_kernel(const int* histM, int* offs, int* bucketBase,
                                                  int nBuck, int nEdges, const float* emb,
                                                  const short* Wf1, ushort* yB, int nNodes,
                                                  int waveOff) {
    if (blockIdx.x == 0) { scanA_body(histM, offs, bucketBase, nBuck, PBLK, nEdges); return; }
    int wid = waveOff + ((int)blockIdx.x - 1) * 4 + ((int)threadIdx.x >> 6);
    transform_body<4, false>(emb, Wf1, yB, nNodes, wid);
}

__global__ __launch_bounds__(256) void mk3_kernel(const int* src, const int* dst, const int* et,
                                                  const float* norm, const int* offs, uint2* meta,
                                                  int nEdges, int nBuck, int chunk,
                                                  const float* emb, const short* Wf1, ushort* yB,
                                                  int nNodes, int waveOff) {
    if ((int)blockIdx.x < PBLK) {
        part_body(src, dst, et, norm, offs, meta, nEdges, nBuck, chunk, blockIdx.x);
        return;
    }
    int wid = waveOff + ((int)blockIdx.x - PBLK) * 4 + ((int)threadIdx.x >> 6);
    transform_body<4, false>(emb, Wf1, yB, nNodes, wid);
}

__global__ __launch_bounds__(256) void mk4_kernel(uint2* meta, const int* bucketBase, int* endOff,
                                                  int nNodes, int nBuck, const float* emb,
                                                  const short* Wf1, ushort* yB, int waveOff) {
    if ((int)blockIdx.x < nBuck) { sortB_body(meta, bucketBase, endOff, nNodes, blockIdx.x); return; }
    int wid = waveOff + ((int)blockIdx.x - nBuck) * 4 + ((int)threadIdx.x >> 6);
    transform_body<4, false>(emb, Wf1, yB, nNodes, wid);
}

// edge1 (hi half) || layer-2 transform (lo half)
__global__ __launch_bounds__(256, 4) void mk6_kernel(const ushort* yB, const uint2* meta,
                                                     const int* endOff, const float* bias1,
                                                     ushort* h1b, const short* Wf2, ushort* y2,
                                                     int nNodes, int eBlocks, int dLo, int dHi,
                                                     int capNodes) {
    if ((int)blockIdx.x < eBlocks) {
        int wid = blockIdx.x * 4 + (threadIdx.x >> 6);
        edge_body<64, ushort, false, 7>(yB, meta, endOff, bias1, h1b, nNodes, 8, wid, dLo, dHi);
        return;
    }
    int wid = ((int)blockIdx.x - eBlocks) * 4 + ((int)threadIdx.x >> 6);
    transform_body<2, true>(h1b, Wf2, y2, capNodes, wid);
}

extern "C" void kernel_launch(void* const* d_in, const int* in_sizes, int n_in,
                              void* d_out, int out_size, void* d_ws, size_t ws_size,
                              hipStream_t stream) {
    const float* emb    = (const float*)d_in[0];
    const float* basis1 = (const float*)d_in[1];
    const float* comp1  = (const float*)d_in[2];
    const float* bias1  = (const float*)d_in[3];
    const float* basis2 = (const float*)d_in[4];
    const float* comp2  = (const float*)d_in[5];
    const float* bias2  = (const float*)d_in[6];
    const int*   src    = (const int*)d_in[7];
    const int*   dst    = (const int*)d_in[8];
    const int*   etype  = (const int*)d_in[9];
    const float* norm   = (const float*)d_in[10];
    float* out = (float*)d_out;

    const int nNodes = in_sizes[0] / 64;   // 200000
    const int nEdges = in_sizes[7];        // 1000000

    const int nBuck = (nNodes + 511) >> BSH;
    const int chunk = (nEdges + PBLK - 1) / PBLK;

    char* ws = (char*)d_ws;
    short* Wf1        = (short*)(ws);
    short* Wf2        = (short*)(ws + 65536);
    int*   histM      = (int*)(ws + 98304);                         // 400,384 B
    int*   offs       = (int*)(ws + 498688);
    int*   bucketBase = (int*)(ws + 899072);
    int*   endOff     = (int*)(ws + 900640);
    size_t offMeta = 1703936;
    uint2* meta       = (uint2*)(ws + offMeta);                     // 8 MB
    size_t offY = offMeta + (size_t)nEdges * 8;

    const size_t yFused = (size_t)nNodes * 512 * 2;  // 204.8 MB
    const size_t yHalf  = (size_t)nNodes * 256 * 2;  // 102.4 MB
    const size_t y2Sz   = (size_t)nNodes * 256 * 2;  // 102.4 MB
    const size_t h1Sz   = (size_t)nNodes * 64 * 2;   // 25.6 MB
    const bool fused = ws_size >= offY + yFused + h1Sz;
    const bool pipe  = ws_size >= offY + yFused + y2Sz + h1Sz;
    ushort* yB = (ushort*)(ws + offY);
    ushort* y2 = pipe ? (ushort*)(ws + offY + yFused) : yB;
    ushort* h1b = pipe ? (ushort*)(ws + offY + yFused + y2Sz)
                       : (ushort*)(ws + offY + (fused ? yFused : yHalf));

    wprep_kernel<<<192, 256, 0, stream>>>(basis1, comp1, basis2, comp2, Wf1, Wf2);

    // ---- T16 wave slices paired with sort stages ----
    const int WT = (nNodes + 31) / 32;
    const int wA = WT * 13 / 100, bA = (wA + 3) / 4;
    const int wB = WT * 10 / 100, bB = (wB + 3) / 4;
    const int wC = WT * 37 / 100, bC = (wC + 3) / 4;
    const int offB = bA * 4, offC = offB + bB * 4, offD = offC + bC * 4;
    const int remD = WT > offD ? WT - offD : 0;
    const int bD = (remD + 3) / 4;
    const int tA = fused ? bA : 0, tB = fused ? bB : 0, tC = fused ? bC : 0, tD = fused ? bD : 0;

    mk1_kernel<<<PBLK + tA, 256, 0, stream>>>(dst, histM, nEdges, nBuck, chunk,
                                              emb, Wf1, yB, nNodes, 0);
    mk2_kernel<<<1 + tB, 256, 0, stream>>>(histM, offs, bucketBase, nBuck, nEdges,
                                           emb, Wf1, yB, nNodes, offB);
    mk3_kernel<<<PBLK + tC, 256, 0, stream>>>(src, dst, etype, norm, offs, meta,
                                              nEdges, nBuck, chunk, emb, Wf1, yB, nNodes, offC);
    mk4_kernel<<<nBuck + tD, 256, 0, stream>>>(meta, bucketBase, endOff, nNodes, nBuck,
                                               emb, Wf1, yB, offD);

    const int D = 8;
    if (fused && pipe) {
        const int nHalf = ((nNodes / 2) + 31) / 32 * 32;         // 100000
        const int ebLo = ((nHalf / D) + 3) / 4;                  // 3125
        const int gHi = (nNodes - nHalf + D - 1) / D;
        const int ebHi = (gHi + 3) / 4;                          // 3125
        const int wLo = nHalf / 32;                              // 3125
        const int tbLo = (wLo + 3) / 4;                          // 782
        const int tbHi = ((WT - wLo) + 3) / 4;                   // 782
        edge_s_kernel<64, ushort, 7><<<ebLo, 256, 0, stream>>>(
            yB, meta, endOff, bias1, h1b, nNodes, 0, nHalf);
        mk6_kernel<<<ebHi + tbLo, 256, 0, stream>>>(
            yB, meta, endOff, bias1, h1b, Wf2, y2, nNodes, ebHi, nHalf, nNodes, nHalf);
        transform_kernel<2, true><<<tbHi, 256, 0, stream>>>(h1b, Wf2, y2, nNodes, wLo);
        const int b32 = ((nNodes + D - 1) / D + 3) / 4;          // 6250
        edge_s_kernel<32, float, 6><<<b32, 256, 0, stream>>>(
            y2, meta, endOff, bias2, out, nNodes, 0, nNodes);
    } else if (fused) {
        const int b64 = ((nNodes + D - 1) / D + 3) / 4;
        edge_s_kernel<64, ushort, 7><<<b64, 256, 0, stream>>>(
            yB, meta, endOff, bias1, h1b, nNodes, 0, nNodes);
        const int tb = (WT + 3) / 4;
        transform_kernel<2, true><<<tb, 256, 0, stream>>>(h1b, Wf2, yB, nNodes, 0);
        edge_s_kernel<32, float, 6><<<b64, 256, 0, stream>>>(
            yB, meta, endOff, bias2, out, nNodes, 0, nNodes);
    } else {
        const int tb = (WT + 3) / 4;
        const int gBlocks = ((nNodes + D - 1) / D + 3) / 4;
        transform_kernel<2, false><<<tb, 256, 0, stream>>>(emb, Wf1, yB, nNodes, 0);
        edge_f_kernel<64, ushort, false><<<gBlocks, 256, 0, stream>>>(
            yB, meta, endOff, bias1, h1b, nNodes, D, 0);
        transform_kernel<2, false><<<tb, 256, 0, stream>>>(emb, Wf1 + 16384, yB, nNodes, 0);
        edge_f_kernel<64, ushort, true><<<gBlocks, 256, 0, stream>>>(
            yB, meta, endOff, bias1, h1b, nNodes, D, 4);
        transform_kernel<2, true><<<tb, 256, 0, stream>>>(h1b, Wf2, yB, nNodes, 0);
        edge_s_kernel<32, float, 6><<<gBlocks, 256, 0, stream>>>(
            yB, meta, endOff, bias2, out, nNodes, 0, nNodes);
    }
}